// Round 7
// baseline (199.759 us; speedup 1.0000x reference)
//
#include <hip/hip_runtime.h>

typedef short bf16x8 __attribute__((ext_vector_type(8)));
typedef float f32x4 __attribute__((ext_vector_type(4)));
typedef float f32x16 __attribute__((ext_vector_type(16)));

#define MFMA16(a,b,c) __builtin_amdgcn_mfma_f32_16x16x32_bf16((a),(b),(c),0,0,0)
#define MFMA32(a,b,c) __builtin_amdgcn_mfma_f32_32x32x16_bf16((a),(b),(c),0,0,0)

static __device__ __forceinline__ unsigned short f2bf(float f){
  unsigned u; __builtin_memcpy(&u, &f, 4);
  u += 0x7fffu + ((u >> 16) & 1u);
  return (unsigned short)(u >> 16);
}

// v_cvt_pk_bf16_f32: D = {lo: bf16(lo), hi: bf16(hi)}  (no builtin on gfx950)
static __device__ __forceinline__ unsigned cvtpk(float lo, float hi){
  unsigned r;
  asm volatile("v_cvt_pk_bf16_f32 %0, %1, %2" : "=v"(r) : "v"(lo), "v"(hi));
  return r;
}
// v_permlane32_swap_b32 a, b:  a[l<32]=b_old[l+32]; b[l>=32]=a_old[l-32]
static __device__ __forceinline__ void pl32swap(unsigned &a, unsigned &b){
  asm volatile("v_permlane32_swap_b32 %0, %1" : "+v"(a), "+v"(b));
}

// async global->LDS DMA, 16 B per lane; LDS dest = wave-uniform base + lane*16
static __device__ __forceinline__ void gload_lds16(const void* g, void* l) {
  __builtin_amdgcn_global_load_lds(
      (__attribute__((address_space(1))) void*)g,
      (__attribute__((address_space(3))) void*)l, 16, 0, 0);
}

// ---------------------------------------------------------------------------
// Stage both weight tensors f32 -> bf16 in ONE launch.
// ---------------------------------------------------------------------------
__global__ __launch_bounds__(256) void cvt_w(
    const float* __restrict__ qkv_w, const float* __restrict__ out_w,
    unsigned short* __restrict__ wq, unsigned short* __restrict__ wo) {
  int i = blockIdx.x * 256 + threadIdx.x;
  if (i < 786432) wq[i] = f2bf(qkv_w[i]);
  else            wo[i - 786432] = f2bf(out_w[i - 786432]);
}

// ---------------------------------------------------------------------------
// T0: x [n][512 c][1024 p] f32 -> xT [n][1024 p][512 c] bf16
// ---------------------------------------------------------------------------
__global__ __launch_bounds__(256) void transpose_cvt(
    const float* __restrict__ in, unsigned short* __restrict__ out)
{
  __shared__ unsigned short tile[32][33];
  const long base = (long)blockIdx.z * 512 * 1024;
  const int t = threadIdx.x, tx = t & 31, ty = t >> 5;
  const int c0 = blockIdx.x * 32, r0 = blockIdx.y * 32;
  const float* ib = in + base;
#pragma unroll
  for (int i = 0; i < 4; ++i)
    tile[ty + i * 8][tx] = f2bf(ib[(long)(r0 + ty + i * 8) * 1024 + c0 + tx]);
  __syncthreads();
  unsigned short* ob = out + base;
#pragma unroll
  for (int i = 0; i < 4; ++i)
    ob[(long)(c0 + ty + i * 8) * 512 + r0 + tx] = tile[tx][ty + i * 8];
}

// ---------------------------------------------------------------------------
// K1: QKV GEMM. R4-proven pipeline: double-buffered LDS, stage(next) before
// compute(cur), one __syncthreads per K-step (compiler-scheduled waits beat
// hand-pinned vmcnt here — R6 post-mortem). XCD-grouped remap. q/k epilogue
// transposes through LDS for 16B-contiguous stores.
// ---------------------------------------------------------------------------
__global__ __launch_bounds__(256, 2) void gemm_qkv(
    const unsigned short* __restrict__ A, const unsigned short* __restrict__ B,
    unsigned short* __restrict__ qkvout, const float* __restrict__ bias)
{
  const int M = 1024, K = 512;
  __shared__ unsigned short SM[4][128 * 64];   // A0 A1 B0 B1, 64 KB
  const int t = threadIdx.x, lane = t & 63, wv = t >> 6;
  const int quad = lane >> 4, ln = lane & 15;

  // bijective XCD remap: L in [0,1536), v = (L%8)*192 + L/8
  const int L = blockIdx.x + 12 * blockIdx.y + 96 * blockIdx.z;
  const int v = (L & 7) * 192 + (L >> 3);
  const int m0 = ((v / 12) & 7) * 128, n0 = (v % 12) * 128;
  const long zb = v / 96;
  A += zb * (long)M * K;

  const int srow = wv * 32 + (lane >> 3);
  const int scol = ((lane & 7) * 8) ^ ((lane >> 3) * 8);

  auto stage = [&](int kt, unsigned short* Ad, unsigned short* Bd) {
#pragma unroll
    for (int i = 0; i < 4; ++i) {
      gload_lds16(&A[(long)(m0 + srow + i * 8) * K + kt + scol],
                  &Ad[(wv * 32 + i * 8) * 64]);
      gload_lds16(&B[(long)(n0 + srow + i * 8) * K + kt + scol],
                  &Bd[(wv * 32 + i * 8) * 64]);
    }
  };

  f32x4 zero = {0.f, 0.f, 0.f, 0.f};
  f32x4 acc[4][4];
#pragma unroll
  for (int i = 0; i < 4; ++i)
#pragma unroll
    for (int j = 0; j < 4; ++j) acc[i][j] = zero;

  const int wm = (wv & 1) * 64, wn = (wv >> 1) * 64;
  const int rsw = (ln & 7) * 8;

  stage(0, SM[0], SM[2]);
  __syncthreads();
  for (int kt8 = 0; kt8 < 8; ++kt8) {
    const int cur = kt8 & 1;
    if (kt8 < 7) stage((kt8 + 1) * 64, SM[cur ^ 1], SM[2 + (cur ^ 1)]);
    const unsigned short* As = SM[cur];
    const unsigned short* Bs = SM[2 + cur];
#pragma unroll
    for (int kk = 0; kk < 64; kk += 32) {
      bf16x8 a[4], b[4];
#pragma unroll
      for (int i = 0; i < 4; ++i)
        a[i] = *(const bf16x8*)&As[(wm + i * 16 + ln) * 64 + ((kk + quad * 8) ^ rsw)];
#pragma unroll
      for (int j = 0; j < 4; ++j)
        b[j] = *(const bf16x8*)&Bs[(wn + j * 16 + ln) * 64 + ((kk + quad * 8) ^ rsw)];
#pragma unroll
      for (int i = 0; i < 4; ++i)
#pragma unroll
        for (int j = 0; j < 4; ++j)
          acc[i][j] = MFMA16(a[i], b[j], acc[i][j]);
    }
    __syncthreads();   // prefetch landed + all waves done with cur buffers
  }

  const int part = n0 >> 9;   // uniform per block: 0=q, 1=k, 2=v
  if (part < 2) {
    // ---- transpose epilogue through LDS: T[p][o'] bf16, padded row 136 ----
    const float qs = (part == 0) ? 0.18033688f : 1.0f;  // 0.125 * log2(e)
    unsigned short (*T)[136] = (unsigned short(*)[136])&SM[0][0];  // 34 KB
#pragma unroll
    for (int j = 0; j < 4; ++j) {
      const int oo = wn + j * 16 + ln;
      const float bb = bias[n0 + oo];
#pragma unroll
      for (int i = 0; i < 4; ++i) {
        const int pp = wm + i * 16 + quad * 4;
        f32x4 vv = acc[i][j];
#pragma unroll
        for (int r = 0; r < 4; ++r)
          T[pp + r][oo] = f2bf((vv[r] + bb) * qs);
      }
    }
    __syncthreads();
    unsigned short* qb = qkvout + (long)part * 8388608;
#pragma unroll
    for (int it = 0; it < 8; ++it) {
      const int idx = it * 256 + t;
      const int p = idx >> 4, c0 = (idx & 15) * 8;
      const int og = n0 + c0;
      const int h = (og >> 6) & 7, d = og & 63;
      bf16x8 val = *(const bf16x8*)&T[p][c0];
      *(bf16x8*)&qb[((long)(zb * 8 + h) * 1024 + m0 + p) * 64 + d] = val;
    }
  } else {
    // ---- v part: [c][p] layout, stores already p-contiguous ----
#pragma unroll
    for (int j = 0; j < 4; ++j) {
      const int o = n0 + wn + j * 16 + ln;
      const float bb = bias[o];
#pragma unroll
      for (int i = 0; i < 4; ++i) {
        const int p = m0 + wm + i * 16 + quad * 4;
        const long cidx = ((long)zb * 512 + (o - 1024)) * 1024 + p;
        f32x4 vv = acc[i][j];
        ushort4 st;
        st.x = f2bf(vv[0] + bb); st.y = f2bf(vv[1] + bb);
        st.z = f2bf(vv[2] + bb); st.w = f2bf(vv[3] + bb);
        *(ushort4*)&qkvout[16777216 + cidx] = st;
      }
    }
  }
}

// ---------------------------------------------------------------------------
// K3: OUT GEMM, same R4-proven pipeline + XCD remap; bias+dropout+residual.
// ---------------------------------------------------------------------------
__global__ __launch_bounds__(256, 2) void gemm_out(
    const unsigned short* __restrict__ A, const unsigned short* __restrict__ B,
    float* __restrict__ C, const float* __restrict__ bias,
    const float* __restrict__ xin, const int* __restrict__ de_ptr)
{
  const int M = 1024, K = 512;
  __shared__ unsigned short SM[4][128 * 64];   // A0 A1 B0 B1, 64 KB
  const int t = threadIdx.x, lane = t & 63, wv = t >> 6;
  const int quad = lane >> 4, ln = lane & 15;

  // bijective XCD remap: L in [0,512), v = (L%8)*64 + L/8
  const int L = blockIdx.x + 4 * blockIdx.y + 32 * blockIdx.z;
  const int v = (L & 7) * 64 + (L >> 3);
  const int m0 = ((v >> 2) & 7) * 128, n0 = (v & 3) * 128;
  const long zb = v >> 5;
  A += zb * (long)M * K;
  C += zb * 512l * M;
  xin += zb * 512l * M;

  const int srow = wv * 32 + (lane >> 3);
  const int scol = ((lane & 7) * 8) ^ ((lane >> 3) * 8);

  auto stage = [&](int kt, unsigned short* Ad, unsigned short* Bd) {
#pragma unroll
    for (int i = 0; i < 4; ++i) {
      gload_lds16(&A[(long)(m0 + srow + i * 8) * K + kt + scol],
                  &Ad[(wv * 32 + i * 8) * 64]);
      gload_lds16(&B[(long)(n0 + srow + i * 8) * K + kt + scol],
                  &Bd[(wv * 32 + i * 8) * 64]);
    }
  };

  f32x4 zero = {0.f, 0.f, 0.f, 0.f};
  f32x4 acc[4][4];
#pragma unroll
  for (int i = 0; i < 4; ++i)
#pragma unroll
    for (int j = 0; j < 4; ++j) acc[i][j] = zero;

  const int wm = (wv & 1) * 64, wn = (wv >> 1) * 64;
  const int rsw = (ln & 7) * 8;

  stage(0, SM[0], SM[2]);
  __syncthreads();
  for (int kt8 = 0; kt8 < 8; ++kt8) {
    const int cur = kt8 & 1;
    if (kt8 < 7) stage((kt8 + 1) * 64, SM[cur ^ 1], SM[2 + (cur ^ 1)]);
    const unsigned short* As = SM[cur];
    const unsigned short* Bs = SM[2 + cur];
#pragma unroll
    for (int kk = 0; kk < 64; kk += 32) {
      bf16x8 a[4], b[4];
#pragma unroll
      for (int i = 0; i < 4; ++i)
        a[i] = *(const bf16x8*)&As[(wm + i * 16 + ln) * 64 + ((kk + quad * 8) ^ rsw)];
#pragma unroll
      for (int j = 0; j < 4; ++j)
        b[j] = *(const bf16x8*)&Bs[(wn + j * 16 + ln) * 64 + ((kk + quad * 8) ^ rsw)];
#pragma unroll
      for (int i = 0; i < 4; ++i)
#pragma unroll
        for (int j = 0; j < 4; ++j)
          acc[i][j] = MFMA16(a[i], b[j], acc[i][j]);
    }
    __syncthreads();
  }

  float dscale = 1.0f / (1.0f - 0.1f * (float)de_ptr[0]);

#pragma unroll
  for (int j = 0; j < 4; ++j) {
    int o = n0 + wn + j * 16 + ln;
    float bb = bias[o];
#pragma unroll
    for (int i = 0; i < 4; ++i) {
      int p = m0 + wm + i * 16 + quad * 4;
      long cidx = (long)o * M + p;
      f32x4 vv = acc[i][j];
      float4 rx = *(const float4*)&xin[cidx];
      float4 st;
      st.x = rx.x + (vv[0] + bb) * dscale;
      st.y = rx.y + (vv[1] + bb) * dscale;
      st.z = rx.z + (vv[2] + bb) * dscale;
      st.w = rx.w + (vv[3] + bb) * dscale;
      *(float4*)&C[cidx] = st;
    }
  }
}

// ---------------------------------------------------------------------------
// Flash attention v11: phase-batched chunk body (T3 lesson applied inside
// attn). 256 blocks x 8 waves x 64 q dual-stream; double-buffered K/V DMA
// with counted vmcnt(4); per chunk 2 super-phases of 2 key-groups:
//   {8 K-frag ds_reads -> 16-MFMA QK cluster (4 indep depth-4 chains)} then
//   per kk: {V-frags->regs (hide under exp2) -> 32-wide exp2 + TREE sum ->
//   cvt_pk/permlane pack -> 8-MFMA PV cluster}.
// ---------------------------------------------------------------------------
__global__ __launch_bounds__(512, 2) void attn_kernel(
    const unsigned short* __restrict__ q_pd, const unsigned short* __restrict__ k_pd,
    const unsigned short* __restrict__ v_cp, unsigned short* __restrict__ y_pc)
{
  __shared__ unsigned short Ks[2][128 * 64];     // 2 x 16 KB, DMA dest
  __shared__ unsigned short Vs[2][64 * 128];     // 2 x 16 KB, DMA dest
  const int t = threadIdx.x, lane = t & 63, wv = t >> 6;   // wv 0..7
  const int l31 = lane & 31, bh8 = (lane >> 5) * 8;
  const int qt = blockIdx.y >> 5;                     // 0..1 q-tile (512 q)
  const int nh = blockIdx.x * 32 + (blockIdx.y & 31); // 0..127
  const int n = nh >> 3, h = nh & 7;
  const int q0 = qt * 512;

  // Q fragments, both streams (B-operand, 32x32x16). Pre-scaled.
  bf16x8 qa[2][4];
#pragma unroll
  for (int qg = 0; qg < 2; ++qg) {
    const unsigned short* qb =
        q_pd + ((long)nh * 1024 + q0 + wv * 64 + qg * 32 + l31) * 64;
#pragma unroll
    for (int ds = 0; ds < 4; ++ds)
      qa[qg][ds] = *(const bf16x8*)(qb + ds * 16 + bh8);
  }

  f32x16 zacc;
#pragma unroll
  for (int r = 0; r < 16; ++r) zacc[r] = 0.f;
  f32x16 o_acc[2][2];
  o_acc[0][0] = zacc; o_acc[0][1] = zacc; o_acc[1][0] = zacc; o_acc[1][1] = zacc;
  float l_acc[2] = {0.f, 0.f};

  const unsigned short* kg0 = k_pd + (long)nh * 1024 * 64;
  const unsigned short* vg0 = v_cp + ((long)n * 512 + h * 64) * 1024;

  // staging coords (8 waves): K 2 issues x 8 rows, V 2 issues x 4 rows.
  const int krow = lane >> 3;
  const int kcol = ((lane & 7) * 8) ^ ((lane >> 3) * 8);
  const int vrow = lane >> 4;
  const int rsw = (lane & 7) * 8;     // K read XOR (frag row&7 == lane&7)
  const int vrsw = (l31 & 15) * 8;    // V read XOR (frag row&15 == l31&15)

  auto stage_kv = [&](int c, int buf) {
    const unsigned short* kg = kg0 + (long)c * 128 * 64;
    const unsigned short* vg = vg0 + c * 128;
    unsigned short* KsD = Ks[buf];
    unsigned short* VsD = Vs[buf];
#pragma unroll
    for (int i = 0; i < 2; ++i) {
      const int vr = ((wv & 1) * 8) + i * 4 + vrow;       // V row & 15
      const int vcol = ((lane & 15) ^ vr) * 8;
      gload_lds16(kg + (long)(wv * 16 + i * 8 + krow) * 64 + kcol,
                  &KsD[(wv * 16 + i * 8) * 64]);
      gload_lds16(vg + (long)(wv * 8 + i * 4 + vrow) * 1024 + vcol,
                  &VsD[(wv * 8 + i * 4) * 128]);
    }
  };

  stage_kv(0, 0);   // prologue

  union U { bf16x8 v; unsigned u[4]; };
  // exp2 + TREE sum + pack (cvt_pk pairs + permlane32 swaps -> 2 B-frags)
  auto sm_pack = [&](const f32x16& sv, bf16x8* paq, float& lac) {
    float e[16];
#pragma unroll
    for (int r = 0; r < 16; ++r) e[r] = __builtin_amdgcn_exp2f(sv[r]);
    float a0 = e[0] + e[1],  a1 = e[2] + e[3],  a2 = e[4] + e[5],  a3 = e[6] + e[7];
    float a4 = e[8] + e[9],  a5 = e[10] + e[11], a6 = e[12] + e[13], a7 = e[14] + e[15];
    float b0 = a0 + a1, b1 = a2 + a3, b2 = a4 + a5, b3 = a6 + a7;
    lac += (b0 + b1) + (b2 + b3);
    unsigned pk4[4][2];
#pragma unroll
    for (int hh = 0; hh < 4; ++hh) {
      pk4[hh][0] = cvtpk(e[4 * hh + 0], e[4 * hh + 1]);
      pk4[hh][1] = cvtpk(e[4 * hh + 2], e[4 * hh + 3]);
    }
#pragma unroll
    for (int hk = 0; hk < 2; ++hk) {
      unsigned x0 = pk4[2 * hk + 1][0], y0 = pk4[2 * hk][0];
      unsigned x1 = pk4[2 * hk + 1][1], y1 = pk4[2 * hk][1];
      pl32swap(x0, y0); pl32swap(x1, y1);
      U u; u.u[0] = y0; u.u[1] = y1; u.u[2] = x0; u.u[3] = x1;
      paq[hk] = u.v;
    }
  };

  for (int c = 0; c < 8; ++c) {
    const int cur = c & 1;
    if (c < 7) {
      stage_kv(c + 1, cur ^ 1);                          // next chunk in flight
      asm volatile("s_waitcnt vmcnt(4)" ::: "memory");   // cur's 4 loads done
    } else {
      asm volatile("s_waitcnt vmcnt(0)" ::: "memory");
    }
    __builtin_amdgcn_s_barrier();     // all waves' cur-chunk DMA landed
    const unsigned short* KsC = Ks[cur];
    const unsigned short* VsC = Vs[cur];

#pragma unroll
    for (int g = 0; g < 2; ++g) {
      // ---- phase 1: all K frags for 2 key-groups ----
      bf16x8 ka[2][4];
#pragma unroll
      for (int kk = 0; kk < 2; ++kk)
#pragma unroll
        for (int ds = 0; ds < 4; ++ds)
          ka[kk][ds] = *(const bf16x8*)
              &KsC[((g * 2 + kk) * 32 + l31) * 64 + ((ds * 16 + bh8) ^ rsw)];
      // ---- phase 2: QK cluster — 16 MFMA, 4 independent depth-4 chains ----
      f32x16 s[2][2];
      s[0][0] = zacc; s[0][1] = zacc; s[1][0] = zacc; s[1][1] = zacc;
      __builtin_amdgcn_s_setprio(1);
#pragma unroll
      for (int ds = 0; ds < 4; ++ds)
#pragma unroll
        for (int kk = 0; kk < 2; ++kk) {
          s[kk][0] = MFMA32(ka[kk][ds], qa[0][ds], s[kk][0]);
          s[kk][1] = MFMA32(ka[kk][ds], qa[1][ds], s[kk][1]);
        }
      __builtin_amdgcn_s_setprio(0);
      // ---- phase 3: per kk, softmax-pack (V reads hide under exp2) + PV ----
#pragma unroll
      for (int kk = 0; kk < 2; ++kk) {
        bf16x8 va[4];
#pragma unroll
        for (int dg = 0; dg < 2; ++dg)
#pragma unroll
          for (int hk = 0; hk < 2; ++hk)
            va[dg * 2 + hk] = *(const bf16x8*)
                &VsC[(dg * 32 + l31) * 128 + ((((g * 2 + kk) * 2 + hk) * 16 + bh8) ^ vrsw)];
        bf16x8 pa[2][2];
        sm_pack(s[kk][0], pa[0], l_acc[0]);
        sm_pack(s[kk][1], pa[1], l_acc[1]);
        __builtin_amdgcn_s_setprio(1);
#pragma unroll
        for (int dg = 0; dg < 2; ++dg)
#pragma unroll
          for (int hk = 0; hk < 2; ++hk) {
            o_acc[dg][0] = MFMA32(va[dg * 2 + hk], pa[0][hk], o_acc[dg][0]);
            o_acc[dg][1] = MFMA32(va[dg * 2 + hk], pa[1][hk], o_acc[dg][1]);
          }
        __builtin_amdgcn_s_setprio(0);
      }
    }
    __builtin_amdgcn_s_barrier();     // done reading cur before its overwrite
  }

  // ---- epilogue: normalize, store y_pc [n][p=q][c = h*64 + d] ----
#pragma unroll
  for (int qg = 0; qg < 2; ++qg) {
    float la = l_acc[qg];
    la += __shfl_xor(la, 32);
    float linv = 1.0f / la;
    const int q = q0 + wv * 64 + qg * 32 + l31;
    unsigned short* yb = y_pc + ((long)n * 1024 + q) * 512 + h * 64;
#pragma unroll
    for (int dg = 0; dg < 2; ++dg) {
      f32x16 o = o_acc[dg][qg];
#pragma unroll
      for (int rq = 0; rq < 4; ++rq) {
        int d0 = dg * 32 + rq * 8 + (bh8 >> 1);   // (lane>>5)*4
        ushort4 st;
        st.x = f2bf(o[rq * 4 + 0] * linv);
        st.y = f2bf(o[rq * 4 + 1] * linv);
        st.z = f2bf(o[rq * 4 + 2] * linv);
        st.w = f2bf(o[rq * 4 + 3] * linv);
        *(ushort4*)&yb[d0] = st;
      }
    }
  }
}

// ---------------------------------------------------------------------------
extern "C" void kernel_launch(void* const* d_in, const int* in_sizes, int n_in,
                              void* d_out, int out_size, void* d_ws, size_t ws_size,
                              hipStream_t stream) {
  (void)in_sizes; (void)n_in; (void)out_size; (void)ws_size;
  const float* x     = (const float*)d_in[0];
  const float* qkv_w = (const float*)d_in[1];
  const float* qkv_b = (const float*)d_in[2];
  const float* out_w = (const float*)d_in[3];
  const float* out_b = (const float*)d_in[4];
  const int* de = (const int*)d_in[5];
  float* out = (float*)d_out;
  unsigned short* ws = (unsigned short*)d_ws;

  // ws layout (shorts), ~66 MiB total:
  //   [0, 8388608)            xT, reused as y_pc
  //   [8388608, 33554432)     qkv: q_pd | k_pd | v_cp (8388608 each)
  //   [33554432, 34340864)    wq bf16 (786432)
  //   [34340864, 34603008)    wo bf16 (262144)
  unsigned short* xT   = ws;
  unsigned short* qkv  = ws + 8388608;
  unsigned short* y_pc = ws;
  unsigned short* wq   = ws + 33554432;
  unsigned short* wo   = wq + 786432;

  cvt_w<<<4096, 256, 0, stream>>>(qkv_w, out_w, wq, wo);

  transpose_cvt<<<dim3(32, 16, 16), 256, 0, stream>>>(x, xT);

  gemm_qkv<<<dim3(12, 8, 16), 256, 0, stream>>>(xT, wq, qkv, qkv_b);

  attn_kernel<<<dim3(4, 64), 512, 0, stream>>>(
      qkv, qkv + 8388608, qkv + 16777216, y_pc);

  gemm_out<<<dim3(4, 8, 16), 256, 0, stream>>>(
      y_pc, wo, out, out_b, x, de);
}

// Round 8
// 181.803 us; speedup vs baseline: 1.0988x; 1.0988x over previous
//
#include <hip/hip_runtime.h>

typedef short bf16x8 __attribute__((ext_vector_type(8)));
typedef float f32x4 __attribute__((ext_vector_type(4)));
typedef float f32x16 __attribute__((ext_vector_type(16)));

#define MFMA16(a,b,c) __builtin_amdgcn_mfma_f32_16x16x32_bf16((a),(b),(c),0,0,0)
#define MFMA32(a,b,c) __builtin_amdgcn_mfma_f32_32x32x16_bf16((a),(b),(c),0,0,0)

static __device__ __forceinline__ unsigned short f2bf(float f){
  unsigned u; __builtin_memcpy(&u, &f, 4);
  u += 0x7fffu + ((u >> 16) & 1u);
  return (unsigned short)(u >> 16);
}

// v_cvt_pk_bf16_f32: D = {lo: bf16(lo), hi: bf16(hi)}  (no builtin on gfx950)
static __device__ __forceinline__ unsigned cvtpk(float lo, float hi){
  unsigned r;
  asm volatile("v_cvt_pk_bf16_f32 %0, %1, %2" : "=v"(r) : "v"(lo), "v"(hi));
  return r;
}
// v_permlane32_swap_b32 a, b:  a[l<32]=b_old[l+32]; b[l>=32]=a_old[l-32]
static __device__ __forceinline__ void pl32swap(unsigned &a, unsigned &b){
  asm volatile("v_permlane32_swap_b32 %0, %1" : "+v"(a), "+v"(b));
}

// async global->LDS DMA, 16 B per lane; LDS dest = wave-uniform base + lane*16
static __device__ __forceinline__ void gload_lds16(const void* g, void* l) {
  __builtin_amdgcn_global_load_lds(
      (__attribute__((address_space(1))) void*)g,
      (__attribute__((address_space(3))) void*)l, 16, 0, 0);
}

// ---------------------------------------------------------------------------
// T0 (+W): x [n][512 c][1024 p] f32 -> xT [n][1024 p][512 c] bf16.
// Blocks with blockIdx.x >= 32 convert the two weight tensors instead
// (2048 extra blocks x 512 elems) — saves a separate launch.
// ---------------------------------------------------------------------------
__global__ __launch_bounds__(256) void transpose_cvt(
    const float* __restrict__ in, unsigned short* __restrict__ out,
    const float* __restrict__ qkv_w, const float* __restrict__ out_w,
    unsigned short* __restrict__ wq, unsigned short* __restrict__ wo)
{
  __shared__ unsigned short tile[32][33];
  if (blockIdx.x >= 32) {   // weight-convert blocks (uniform per block)
    const int b = (blockIdx.x - 32) + 8 * (blockIdx.y + 16 * blockIdx.z);
    const int i = b * 512 + threadIdx.x * 2;
    float2 v; unsigned short* dst;
    if (i < 786432) { v = *(const float2*)&qkv_w[i]; dst = &wq[i]; }
    else { v = *(const float2*)&out_w[i - 786432]; dst = &wo[i - 786432]; }
    dst[0] = f2bf(v.x); dst[1] = f2bf(v.y);
    return;
  }
  const long base = (long)blockIdx.z * 512 * 1024;
  const int t = threadIdx.x, tx = t & 31, ty = t >> 5;
  const int c0 = blockIdx.x * 32, r0 = blockIdx.y * 32;
  const float* ib = in + base;
#pragma unroll
  for (int i = 0; i < 4; ++i)
    tile[ty + i * 8][tx] = f2bf(ib[(long)(r0 + ty + i * 8) * 1024 + c0 + tx]);
  __syncthreads();
  unsigned short* ob = out + base;
#pragma unroll
  for (int i = 0; i < 4; ++i)
    ob[(long)(c0 + ty + i * 8) * 512 + r0 + tx] = tile[tx][ty + i * 8];
}

// ---------------------------------------------------------------------------
// K1: QKV GEMM. R4-proven pipeline: double-buffered LDS, stage(next) before
// compute(cur), one __syncthreads per K-step. XCD-grouped remap. q/k epilogue
// transposes through LDS for 16B-contiguous stores.
// ---------------------------------------------------------------------------
__global__ __launch_bounds__(256, 2) void gemm_qkv(
    const unsigned short* __restrict__ A, const unsigned short* __restrict__ B,
    unsigned short* __restrict__ qkvout, const float* __restrict__ bias)
{
  const int M = 1024, K = 512;
  __shared__ unsigned short SM[4][128 * 64];   // A0 A1 B0 B1, 64 KB
  const int t = threadIdx.x, lane = t & 63, wv = t >> 6;
  const int quad = lane >> 4, ln = lane & 15;

  // bijective XCD remap: L in [0,1536), v = (L%8)*192 + L/8
  const int L = blockIdx.x + 12 * blockIdx.y + 96 * blockIdx.z;
  const int v = (L & 7) * 192 + (L >> 3);
  const int m0 = ((v / 12) & 7) * 128, n0 = (v % 12) * 128;
  const long zb = v / 96;
  A += zb * (long)M * K;

  const int srow = wv * 32 + (lane >> 3);
  const int scol = ((lane & 7) * 8) ^ ((lane >> 3) * 8);

  auto stage = [&](int kt, unsigned short* Ad, unsigned short* Bd) {
#pragma unroll
    for (int i = 0; i < 4; ++i) {
      gload_lds16(&A[(long)(m0 + srow + i * 8) * K + kt + scol],
                  &Ad[(wv * 32 + i * 8) * 64]);
      gload_lds16(&B[(long)(n0 + srow + i * 8) * K + kt + scol],
                  &Bd[(wv * 32 + i * 8) * 64]);
    }
  };

  f32x4 zero = {0.f, 0.f, 0.f, 0.f};
  f32x4 acc[4][4];
#pragma unroll
  for (int i = 0; i < 4; ++i)
#pragma unroll
    for (int j = 0; j < 4; ++j) acc[i][j] = zero;

  const int wm = (wv & 1) * 64, wn = (wv >> 1) * 64;
  const int rsw = (ln & 7) * 8;

  stage(0, SM[0], SM[2]);
  __syncthreads();
  for (int kt8 = 0; kt8 < 8; ++kt8) {
    const int cur = kt8 & 1;
    if (kt8 < 7) stage((kt8 + 1) * 64, SM[cur ^ 1], SM[2 + (cur ^ 1)]);
    const unsigned short* As = SM[cur];
    const unsigned short* Bs = SM[2 + cur];
#pragma unroll
    for (int kk = 0; kk < 64; kk += 32) {
      bf16x8 a[4], b[4];
#pragma unroll
      for (int i = 0; i < 4; ++i)
        a[i] = *(const bf16x8*)&As[(wm + i * 16 + ln) * 64 + ((kk + quad * 8) ^ rsw)];
#pragma unroll
      for (int j = 0; j < 4; ++j)
        b[j] = *(const bf16x8*)&Bs[(wn + j * 16 + ln) * 64 + ((kk + quad * 8) ^ rsw)];
#pragma unroll
      for (int i = 0; i < 4; ++i)
#pragma unroll
        for (int j = 0; j < 4; ++j)
          acc[i][j] = MFMA16(a[i], b[j], acc[i][j]);
    }
    __syncthreads();   // prefetch landed + all waves done with cur buffers
  }

  const int part = n0 >> 9;   // uniform per block: 0=q, 1=k, 2=v
  if (part < 2) {
    // ---- transpose epilogue through LDS: T[p][o'] bf16, padded row 136 ----
    const float qs = (part == 0) ? 0.18033688f : 1.0f;  // 0.125 * log2(e)
    unsigned short (*T)[136] = (unsigned short(*)[136])&SM[0][0];  // 34 KB
#pragma unroll
    for (int j = 0; j < 4; ++j) {
      const int oo = wn + j * 16 + ln;
      const float bb = bias[n0 + oo];
#pragma unroll
      for (int i = 0; i < 4; ++i) {
        const int pp = wm + i * 16 + quad * 4;
        f32x4 vv = acc[i][j];
#pragma unroll
        for (int r = 0; r < 4; ++r)
          T[pp + r][oo] = f2bf((vv[r] + bb) * qs);
      }
    }
    __syncthreads();
    unsigned short* qb = qkvout + (long)part * 8388608;
#pragma unroll
    for (int it = 0; it < 8; ++it) {
      const int idx = it * 256 + t;
      const int p = idx >> 4, c0 = (idx & 15) * 8;
      const int og = n0 + c0;
      const int h = (og >> 6) & 7, d = og & 63;
      bf16x8 val = *(const bf16x8*)&T[p][c0];
      *(bf16x8*)&qb[((long)(zb * 8 + h) * 1024 + m0 + p) * 64 + d] = val;
    }
  } else {
    // ---- v part: [c][p] layout, stores already p-contiguous ----
#pragma unroll
    for (int j = 0; j < 4; ++j) {
      const int o = n0 + wn + j * 16 + ln;
      const float bb = bias[o];
#pragma unroll
      for (int i = 0; i < 4; ++i) {
        const int p = m0 + wm + i * 16 + quad * 4;
        const long cidx = ((long)zb * 512 + (o - 1024)) * 1024 + p;
        f32x4 vv = acc[i][j];
        ushort4 st;
        st.x = f2bf(vv[0] + bb); st.y = f2bf(vv[1] + bb);
        st.z = f2bf(vv[2] + bb); st.w = f2bf(vv[3] + bb);
        *(ushort4*)&qkvout[16777216 + cidx] = st;
      }
    }
  }
}

// ---------------------------------------------------------------------------
// K3: OUT GEMM, same R4-proven pipeline + XCD remap; bias+dropout+residual.
// ---------------------------------------------------------------------------
__global__ __launch_bounds__(256, 2) void gemm_out(
    const unsigned short* __restrict__ A, const unsigned short* __restrict__ B,
    float* __restrict__ C, const float* __restrict__ bias,
    const float* __restrict__ xin, const int* __restrict__ de_ptr)
{
  const int M = 1024, K = 512;
  __shared__ unsigned short SM[4][128 * 64];   // A0 A1 B0 B1, 64 KB
  const int t = threadIdx.x, lane = t & 63, wv = t >> 6;
  const int quad = lane >> 4, ln = lane & 15;

  // bijective XCD remap: L in [0,512), v = (L%8)*64 + L/8
  const int L = blockIdx.x + 4 * blockIdx.y + 32 * blockIdx.z;
  const int v = (L & 7) * 64 + (L >> 3);
  const int m0 = ((v >> 2) & 7) * 128, n0 = (v & 3) * 128;
  const long zb = v >> 5;
  A += zb * (long)M * K;
  C += zb * 512l * M;
  xin += zb * 512l * M;

  const int srow = wv * 32 + (lane >> 3);
  const int scol = ((lane & 7) * 8) ^ ((lane >> 3) * 8);

  auto stage = [&](int kt, unsigned short* Ad, unsigned short* Bd) {
#pragma unroll
    for (int i = 0; i < 4; ++i) {
      gload_lds16(&A[(long)(m0 + srow + i * 8) * K + kt + scol],
                  &Ad[(wv * 32 + i * 8) * 64]);
      gload_lds16(&B[(long)(n0 + srow + i * 8) * K + kt + scol],
                  &Bd[(wv * 32 + i * 8) * 64]);
    }
  };

  f32x4 zero = {0.f, 0.f, 0.f, 0.f};
  f32x4 acc[4][4];
#pragma unroll
  for (int i = 0; i < 4; ++i)
#pragma unroll
    for (int j = 0; j < 4; ++j) acc[i][j] = zero;

  const int wm = (wv & 1) * 64, wn = (wv >> 1) * 64;
  const int rsw = (ln & 7) * 8;

  stage(0, SM[0], SM[2]);
  __syncthreads();
  for (int kt8 = 0; kt8 < 8; ++kt8) {
    const int cur = kt8 & 1;
    if (kt8 < 7) stage((kt8 + 1) * 64, SM[cur ^ 1], SM[2 + (cur ^ 1)]);
    const unsigned short* As = SM[cur];
    const unsigned short* Bs = SM[2 + cur];
#pragma unroll
    for (int kk = 0; kk < 64; kk += 32) {
      bf16x8 a[4], b[4];
#pragma unroll
      for (int i = 0; i < 4; ++i)
        a[i] = *(const bf16x8*)&As[(wm + i * 16 + ln) * 64 + ((kk + quad * 8) ^ rsw)];
#pragma unroll
      for (int j = 0; j < 4; ++j)
        b[j] = *(const bf16x8*)&Bs[(wn + j * 16 + ln) * 64 + ((kk + quad * 8) ^ rsw)];
#pragma unroll
      for (int i = 0; i < 4; ++i)
#pragma unroll
        for (int j = 0; j < 4; ++j)
          acc[i][j] = MFMA16(a[i], b[j], acc[i][j]);
    }
    __syncthreads();
  }

  float dscale = 1.0f / (1.0f - 0.1f * (float)de_ptr[0]);

#pragma unroll
  for (int j = 0; j < 4; ++j) {
    int o = n0 + wn + j * 16 + ln;
    float bb = bias[o];
#pragma unroll
    for (int i = 0; i < 4; ++i) {
      int p = m0 + wm + i * 16 + quad * 4;
      long cidx = (long)o * M + p;
      f32x4 vv = acc[i][j];
      float4 rx = *(const float4*)&xin[cidx];
      float4 st;
      st.x = rx.x + (vv[0] + bb) * dscale;
      st.y = rx.y + (vv[1] + bb) * dscale;
      st.z = rx.z + (vv[2] + bb) * dscale;
      st.w = rx.w + (vv[3] + bb) * dscale;
      *(float4*)&C[cidx] = st;
    }
  }
}

// ---------------------------------------------------------------------------
// Flash attention v12: software-pipelined key-group loop. Per kgi:
//   issue QK(kgi+1) MFMA cluster FIRST (no dep on current softmax), then run
//   sm_pack(kgi) exp2/pack on the VALU while those MFMAs drain, then PV(kgi).
// Static 2-state s-buffers (sA/sB, rule #20). 256 blocks x 8 waves x 64 q
// dual-stream, dbuf K/V DMA with counted vmcnt(4), XOR-swizzled LDS.
// ---------------------------------------------------------------------------
__global__ __launch_bounds__(512, 2) void attn_kernel(
    const unsigned short* __restrict__ q_pd, const unsigned short* __restrict__ k_pd,
    const unsigned short* __restrict__ v_cp, unsigned short* __restrict__ y_pc)
{
  __shared__ unsigned short Ks[2][128 * 64];     // 2 x 16 KB, DMA dest
  __shared__ unsigned short Vs[2][64 * 128];     // 2 x 16 KB, DMA dest
  const int t = threadIdx.x, lane = t & 63, wv = t >> 6;   // wv 0..7
  const int l31 = lane & 31, bh8 = (lane >> 5) * 8;
  const int qt = blockIdx.y >> 5;                     // 0..1 q-tile (512 q)
  const int nh = blockIdx.x * 32 + (blockIdx.y & 31); // 0..127
  const int n = nh >> 3, h = nh & 7;
  const int q0 = qt * 512;

  // Q fragments, both streams (B-operand, 32x32x16). Pre-scaled.
  bf16x8 qa[2][4];
#pragma unroll
  for (int qg = 0; qg < 2; ++qg) {
    const unsigned short* qb =
        q_pd + ((long)nh * 1024 + q0 + wv * 64 + qg * 32 + l31) * 64;
#pragma unroll
    for (int ds = 0; ds < 4; ++ds)
      qa[qg][ds] = *(const bf16x8*)(qb + ds * 16 + bh8);
  }

  f32x16 zacc;
#pragma unroll
  for (int r = 0; r < 16; ++r) zacc[r] = 0.f;
  f32x16 o_acc[2][2];
  o_acc[0][0] = zacc; o_acc[0][1] = zacc; o_acc[1][0] = zacc; o_acc[1][1] = zacc;
  float l_acc[2] = {0.f, 0.f};

  const unsigned short* kg0 = k_pd + (long)nh * 1024 * 64;
  const unsigned short* vg0 = v_cp + ((long)n * 512 + h * 64) * 1024;

  // staging coords (8 waves): K 2 issues x 8 rows, V 2 issues x 4 rows.
  const int krow = lane >> 3;
  const int kcol = ((lane & 7) * 8) ^ ((lane >> 3) * 8);
  const int vrow = lane >> 4;
  const int rsw = (lane & 7) * 8;     // K read XOR (frag row&7 == lane&7)
  const int vrsw = (l31 & 15) * 8;    // V read XOR (frag row&15 == l31&15)

  auto stage_kv = [&](int c, int buf) {
    const unsigned short* kg = kg0 + (long)c * 128 * 64;
    const unsigned short* vg = vg0 + c * 128;
    unsigned short* KsD = Ks[buf];
    unsigned short* VsD = Vs[buf];
#pragma unroll
    for (int i = 0; i < 2; ++i) {
      const int vr = ((wv & 1) * 8) + i * 4 + vrow;       // V row & 15
      const int vcol = ((lane & 15) ^ vr) * 8;
      gload_lds16(kg + (long)(wv * 16 + i * 8 + krow) * 64 + kcol,
                  &KsD[(wv * 16 + i * 8) * 64]);
      gload_lds16(vg + (long)(wv * 8 + i * 4 + vrow) * 1024 + vcol,
                  &VsD[(wv * 8 + i * 4) * 128]);
    }
  };

  stage_kv(0, 0);   // prologue

  union U { bf16x8 v; unsigned u[4]; };
  // exp2 + TREE sum + pack (cvt_pk pairs + permlane32 swaps -> 2 B-frags)
  auto sm_pack = [&](const f32x16& sv, bf16x8* paq, float& lac) {
    float e[16];
#pragma unroll
    for (int r = 0; r < 16; ++r) e[r] = __builtin_amdgcn_exp2f(sv[r]);
    float a0 = e[0] + e[1],  a1 = e[2] + e[3],  a2 = e[4] + e[5],  a3 = e[6] + e[7];
    float a4 = e[8] + e[9],  a5 = e[10] + e[11], a6 = e[12] + e[13], a7 = e[14] + e[15];
    float b0 = a0 + a1, b1 = a2 + a3, b2 = a4 + a5, b3 = a6 + a7;
    lac += (b0 + b1) + (b2 + b3);
    unsigned pk4[4][2];
#pragma unroll
    for (int hh = 0; hh < 4; ++hh) {
      pk4[hh][0] = cvtpk(e[4 * hh + 0], e[4 * hh + 1]);
      pk4[hh][1] = cvtpk(e[4 * hh + 2], e[4 * hh + 3]);
    }
#pragma unroll
    for (int hk = 0; hk < 2; ++hk) {
      unsigned x0 = pk4[2 * hk + 1][0], y0 = pk4[2 * hk][0];
      unsigned x1 = pk4[2 * hk + 1][1], y1 = pk4[2 * hk][1];
      pl32swap(x0, y0); pl32swap(x1, y1);
      U u; u.u[0] = y0; u.u[1] = y1; u.u[2] = x0; u.u[3] = x1;
      paq[hk] = u.v;
    }
  };

  // QK cluster for key-group kgi -> s (both streams)
  auto qk_issue = [&](const unsigned short* KsC, int kgi, f32x16* s) {
    bf16x8 ka[4];
#pragma unroll
    for (int ds = 0; ds < 4; ++ds)
      ka[ds] = *(const bf16x8*)
          &KsC[(kgi * 32 + l31) * 64 + ((ds * 16 + bh8) ^ rsw)];
    s[0] = zacc; s[1] = zacc;
    __builtin_amdgcn_s_setprio(1);
#pragma unroll
    for (int ds = 0; ds < 4; ++ds) {
      s[0] = MFMA32(ka[ds], qa[0][ds], s[0]);
      s[1] = MFMA32(ka[ds], qa[1][ds], s[1]);
    }
    __builtin_amdgcn_s_setprio(0);
  };

  // pipeline stage: issue QK(kgi+1) into snxt, then softmax+PV of scur (kgi)
  auto body = [&](const unsigned short* KsC, const unsigned short* VsC,
                  int kgi, f32x16* scur, f32x16* snxt) {
    if (kgi < 3) qk_issue(KsC, kgi + 1, snxt);
    bf16x8 va[4];
#pragma unroll
    for (int dg = 0; dg < 2; ++dg)
#pragma unroll
      for (int hk = 0; hk < 2; ++hk)
        va[dg * 2 + hk] = *(const bf16x8*)
            &VsC[(dg * 32 + l31) * 128 + (((kgi * 2 + hk) * 16 + bh8) ^ vrsw)];
    bf16x8 pa[2][2];
    sm_pack(scur[0], pa[0], l_acc[0]);
    sm_pack(scur[1], pa[1], l_acc[1]);
    __builtin_amdgcn_s_setprio(1);
#pragma unroll
    for (int dg = 0; dg < 2; ++dg)
#pragma unroll
      for (int hk = 0; hk < 2; ++hk) {
        o_acc[dg][0] = MFMA32(va[dg * 2 + hk], pa[0][hk], o_acc[dg][0]);
        o_acc[dg][1] = MFMA32(va[dg * 2 + hk], pa[1][hk], o_acc[dg][1]);
      }
    __builtin_amdgcn_s_setprio(0);
  };

  for (int c = 0; c < 8; ++c) {
    const int cur = c & 1;
    if (c < 7) {
      stage_kv(c + 1, cur ^ 1);                          // next chunk in flight
      asm volatile("s_waitcnt vmcnt(4)" ::: "memory");   // cur's 4 loads done
    } else {
      asm volatile("s_waitcnt vmcnt(0)" ::: "memory");
    }
    __builtin_amdgcn_s_barrier();     // all waves' cur-chunk DMA landed
    const unsigned short* KsC = Ks[cur];
    const unsigned short* VsC = Vs[cur];

    f32x16 sA[2], sB[2];
    qk_issue(KsC, 0, sA);             // fill the pipeline
    body(KsC, VsC, 0, sA, sB);
    body(KsC, VsC, 1, sB, sA);
    body(KsC, VsC, 2, sA, sB);
    body(KsC, VsC, 3, sB, sA);        // drain (no QK issue)

    __builtin_amdgcn_s_barrier();     // done reading cur before its overwrite
  }

  // ---- epilogue: normalize, store y_pc [n][p=q][c = h*64 + d] ----
#pragma unroll
  for (int qg = 0; qg < 2; ++qg) {
    float la = l_acc[qg];
    la += __shfl_xor(la, 32);
    float linv = 1.0f / la;
    const int q = q0 + wv * 64 + qg * 32 + l31;
    unsigned short* yb = y_pc + ((long)n * 1024 + q) * 512 + h * 64;
#pragma unroll
    for (int dg = 0; dg < 2; ++dg) {
      f32x16 o = o_acc[dg][qg];
#pragma unroll
      for (int rq = 0; rq < 4; ++rq) {
        int d0 = dg * 32 + rq * 8 + (bh8 >> 1);   // (lane>>5)*4
        ushort4 st;
        st.x = f2bf(o[rq * 4 + 0] * linv);
        st.y = f2bf(o[rq * 4 + 1] * linv);
        st.z = f2bf(o[rq * 4 + 2] * linv);
        st.w = f2bf(o[rq * 4 + 3] * linv);
        *(ushort4*)&yb[d0] = st;
      }
    }
  }
}

// ---------------------------------------------------------------------------
extern "C" void kernel_launch(void* const* d_in, const int* in_sizes, int n_in,
                              void* d_out, int out_size, void* d_ws, size_t ws_size,
                              hipStream_t stream) {
  (void)in_sizes; (void)n_in; (void)out_size; (void)ws_size;
  const float* x     = (const float*)d_in[0];
  const float* qkv_w = (const float*)d_in[1];
  const float* qkv_b = (const float*)d_in[2];
  const float* out_w = (const float*)d_in[3];
  const float* out_b = (const float*)d_in[4];
  const int* de = (const int*)d_in[5];
  float* out = (float*)d_out;
  unsigned short* ws = (unsigned short*)d_ws;

  // ws layout (shorts), ~66 MiB total:
  //   [0, 8388608)            xT, reused as y_pc
  //   [8388608, 33554432)     qkv: q_pd | k_pd | v_cp (8388608 each)
  //   [33554432, 34340864)    wq bf16 (786432)
  //   [34340864, 34603008)    wo bf16 (262144)
  unsigned short* xT   = ws;
  unsigned short* qkv  = ws + 8388608;
  unsigned short* y_pc = ws;
  unsigned short* wq   = ws + 33554432;
  unsigned short* wo   = wq + 786432;

  transpose_cvt<<<dim3(40, 16, 16), 256, 0, stream>>>(
      x, xT, qkv_w, out_w, wq, wo);

  gemm_qkv<<<dim3(12, 8, 16), 256, 0, stream>>>(xT, wq, qkv, qkv_b);

  attn_kernel<<<dim3(4, 64), 512, 0, stream>>>(
      qkv, qkv + 8388608, qkv + 16777216, y_pc);

  gemm_out<<<dim3(4, 8, 16), 256, 0, stream>>>(
      y_pc, wo, out, out_b, x, de);
}